// Round 8
// baseline (194.189 us; speedup 1.0000x reference)
//
#include <hip/hip_runtime.h>

#define N_NODES 100000
#define N_EDGES 1600000
#define DIM 128
#define NH 4

#define NPB 512                                   // nodes per coarse bucket
#define NB 196                                    // ceil(N_NODES / NPB)
#define BCHUNK 8192                               // edges per block (bucket passes)
#define BEPT 32                                   // BCHUNK / 256
#define NBLK ((N_EDGES + BCHUNK - 1) / BCHUNK)    // 196

typedef __attribute__((ext_vector_type(8))) short bf16x8;
typedef __attribute__((ext_vector_type(4))) float f32x4;
typedef __attribute__((ext_vector_type(8))) unsigned short u16x8;

// ws layout, BYTE offsets (16B-aligned where it matters):
//   bcnt   : [0, 1024)           int[256] coarse bucket counts
//   bbase  : [1024, 2048)        int[256] bucket bases (excl scan)
//   bcur   : [2048, 3072)        int[256] bucket fill cursors
//   rowoff : [4096, 405504)      int[100001] node-level CSR offsets
//   csr    : [405504, 6805504)   int[1.6M] src ids bucketed+sorted by dst
//   wpack  : [6805504, 6871040)  bf16 MFMA-packed Ws|Wn
//   bavg   : [6871040, 6871552)  f32[128]
//   hb     : [6871552, 32471552) bf16 copy of h (25.6MB)
//   ebuf   : aliases hb region   int[1.6M] packed (src<<9|dstlo); dead before h2bf16
#define B_BCNT   0u
#define B_BBASE  1024u
#define B_BCUR   2048u
#define B_ROWOFF 4096u
#define B_CSR    405504u
#define B_WPACK  6805504u
#define B_BAVG   6871040u
#define B_HB     6871552u
#define B_EBUF   6871552u
#define NEED_BF16 32869376ull

// branchless RTNE f32->bf16 (finite inputs; no NaN path)
__device__ inline unsigned short f2bf(float x) {
    union { float f; unsigned u; } v; v.f = x;
    unsigned r = v.u + 0x7fffu + ((v.u >> 16) & 1u);
    return (unsigned short)(r >> 16);
}

// ---------------------------------------------------------------------------
// Head-average weights (mean over heads commutes with einsum+mean), pack into
// MFMA B-frag order. Block 0 also zeroes bcnt (replaces a memset dispatch).
// ---------------------------------------------------------------------------
__global__ __launch_bounds__(256) void prep_weights_kernel(
    const float* __restrict__ Ws, const float* __restrict__ Wn,
    const float* __restrict__ b, unsigned short* __restrict__ wpack,
    float* __restrict__ bavg, int* __restrict__ bcnt) {
    if (blockIdx.x == 0) bcnt[threadIdx.x] = 0;
    int i = blockIdx.x * 256 + threadIdx.x;  // i = k*128 + o
    if (i < DIM * DIM) {
        float s = 0.f, n = 0.f;
#pragma unroll
        for (int hh = 0; hh < NH; ++hh) {
            s += Ws[hh * DIM * DIM + i];
            n += Wn[hh * DIM * DIM + i];
        }
        s *= 0.25f; n *= 0.25f;
        int k = i >> 7, o = i & 127;
        int nt = o >> 4, lanelo = o & 15;
        int ks = k >> 5, lanehi = (k & 31) >> 3, e = k & 7;
        int pos = (((nt * 4 + ks) * 64) + lanehi * 16 + lanelo) * 8 + e;
        wpack[pos] = f2bf(s);
        wpack[16384 + pos] = f2bf(n);
    }
    if (i < DIM) {
        float bb = 0.f;
#pragma unroll
        for (int hh = 0; hh < NH; ++hh) bb += b[hh * DIM + i];
        bavg[i] = 0.25f * bb;
    }
}

// ---------------------------------------------------------------------------
// h -> bf16 copy (halves gather read stream; direct MFMA A-frags)
// ---------------------------------------------------------------------------
__global__ __launch_bounds__(256) void h2bf16_kernel(const float* __restrict__ h,
                                                     unsigned short* __restrict__ hb) {
    int i = blockIdx.x * 256 + threadIdx.x;  // 8 elems/thread
    const float4* p = reinterpret_cast<const float4*>(h) + (size_t)i * 2;
    float4 a = p[0], c = p[1];
    u16x8 r;
    r[0] = f2bf(a.x); r[1] = f2bf(a.y); r[2] = f2bf(a.z); r[3] = f2bf(a.w);
    r[4] = f2bf(c.x); r[5] = f2bf(c.y); r[6] = f2bf(c.z); r[7] = f2bf(c.w);
    reinterpret_cast<u16x8*>(hb)[i] = r;
}

// ---------------------------------------------------------------------------
// P1a: coarse histogram (bucket = dst>>9) via LDS counters
// ---------------------------------------------------------------------------
__global__ __launch_bounds__(256) void bucket_hist_kernel(const int* __restrict__ dst,
                                                          int* __restrict__ bcnt) {
    __shared__ int lc[256];
    int t = threadIdx.x;
    lc[t] = 0;
    __syncthreads();
    int e0 = blockIdx.x * BCHUNK;
#pragma unroll 4
    for (int j = 0; j < BEPT; ++j) {
        int e = e0 + j * 256 + t;
        if (e < N_EDGES) atomicAdd(&lc[dst[e] >> 9], 1);
    }
    __syncthreads();
    if (lc[t]) atomicAdd(&bcnt[t], lc[t]);
}

// ---------------------------------------------------------------------------
// P1b: scan 256 bucket counts -> bases; init cursors
// ---------------------------------------------------------------------------
__global__ __launch_bounds__(256) void bucket_scan_kernel(const int* __restrict__ bcnt,
                                                          int* __restrict__ bbase,
                                                          int* __restrict__ bcur) {
    __shared__ int s[256];
    int t = threadIdx.x;
    int v = bcnt[t];
    s[t] = v;
    __syncthreads();
    for (int off = 1; off < 256; off <<= 1) {
        int add = (t >= off) ? s[t - off] : 0;
        __syncthreads();
        s[t] += add;
        __syncthreads();
    }
    int ex = s[t] - v;
    bbase[t] = ex;
    bcur[t] = ex;
}

// ---------------------------------------------------------------------------
// P1c: bucket the edges. Block stages 8192 packed edges in LDS, reserves one
// contiguous chunk per bucket (1 global atomic/bucket/block), appends ~32-edge
// (128B, full-cacheline) runs. Packed word: (src<<9) | (dst & 511).
// ---------------------------------------------------------------------------
__global__ __launch_bounds__(256) void bucket_scatter_kernel(const int* __restrict__ src,
                                                             const int* __restrict__ dst,
                                                             int* __restrict__ bcur,
                                                             int* __restrict__ ebuf) {
    __shared__ int stage[BCHUNK];
    __shared__ int lc[256], lbase[256], lpos[256];
    int t = threadIdx.x;
    lc[t] = 0;
    lpos[t] = 0;
    __syncthreads();
    int e0 = blockIdx.x * BCHUNK;
#pragma unroll 4
    for (int j = 0; j < BEPT; ++j) {
        int e = e0 + j * 256 + t;
        if (e < N_EDGES) {
            int d = dst[e];
            stage[j * 256 + t] = (src[e] << 9) | (d & (NPB - 1));
            atomicAdd(&lc[d >> 9], 1);
        }
    }
    __syncthreads();
    if (lc[t]) lbase[t] = atomicAdd(&bcur[t], lc[t]);
    __syncthreads();
#pragma unroll 4
    for (int j = 0; j < BEPT; ++j) {
        int e = e0 + j * 256 + t;
        if (e < N_EDGES) {
            int b = dst[e] >> 9;
            int o = atomicAdd(&lpos[b], 1);
            ebuf[lbase[b] + o] = stage[j * 256 + t];
        }
    }
}

// ---------------------------------------------------------------------------
// P2: one block per bucket. Local 512-slot hist + scan -> rowoff, then scatter
// src into csr within the bucket's contiguous (L2-resident) window.
// ---------------------------------------------------------------------------
__global__ __launch_bounds__(256) void csr_build_kernel(const int* __restrict__ bcnt,
                                                        const int* __restrict__ bbase,
                                                        const int* __restrict__ ebuf,
                                                        int* __restrict__ rowoff,
                                                        int* __restrict__ csr) {
    __shared__ int h[NPB], off[NPB], cur[NPB], ss[256];
    int b = blockIdx.x, t = threadIdx.x;
    int cnt = bcnt[b], base = bbase[b];
    h[t] = 0; h[t + 256] = 0;
    cur[t] = 0; cur[t + 256] = 0;
    __syncthreads();
    for (int i = t; i < cnt; i += 256) atomicAdd(&h[ebuf[base + i] & (NPB - 1)], 1);
    __syncthreads();
    int e0 = h[2 * t], e1 = h[2 * t + 1];
    ss[t] = e0 + e1;
    __syncthreads();
    for (int o = 1; o < 256; o <<= 1) {
        int add = (t >= o) ? ss[t - o] : 0;
        __syncthreads();
        ss[t] += add;
        __syncthreads();
    }
    int ex = ss[t] - (e0 + e1);
    off[2 * t] = ex;
    off[2 * t + 1] = ex + e0;
    __syncthreads();
    int n0 = b * NPB;
#pragma unroll
    for (int k = 0; k < 2; ++k) {
        int s2 = t + k * 256;
        int n = n0 + s2;
        if (n <= N_NODES) rowoff[n] = base + off[s2];
    }
    for (int i = t; i < cnt; i += 256) {
        int p = ebuf[base + i];
        int nl = p & (NPB - 1);
        int o = atomicAdd(&cur[nl], 1);
        csr[base + off[nl] + o] = p >> 9;
    }
}

// ---------------------------------------------------------------------------
// FUSED gather-mean + MFMA GEMM. Block = 64 nodes, 4 waves; wave owns 16 nodes.
// Phase 1: wave gathers each of its nodes' neighbor-mean rows (4 edge-slots x
// 16 lanes x 16B), rounds to bf16 (same rounding point as before -> bitwise-
// identical output), stores into LDS (wave-private rows -> no __syncthreads).
// Phase 2: MFMA GEMM out[n] = h[n]@Ws + hn[n]@Wn + bavg; na frags from LDS.
// LDS rows padded +8 bf16 so phase-2 ds_read_b128 is mostly 2-way (free).
// ---------------------------------------------------------------------------
template <bool BF>
__global__ __launch_bounds__(256) void gather_gemm_kernel(
    const float* __restrict__ h, const unsigned short* __restrict__ hb,
    const int* __restrict__ rowoff, const int* __restrict__ csr,
    float* __restrict__ out, const unsigned short* __restrict__ wpack,
    const float* __restrict__ bavg) {
    __shared__ unsigned short hnl[64][DIM + 8];
    const int lane = threadIdx.x & 63;
    const int wid = threadIdx.x >> 6;
    const int node_base = blockIdx.x * 64 + wid * 16;
    const int g = lane >> 4;   // edge slot
    const int c = lane & 15;   // 16B chunk within row

    // ---- Phase 1: gather means for my 16 nodes into LDS ----
    for (int r = 0; r < 16; ++r) {
        const int node = node_base + r;
        float a0 = 0.f, a1 = 0.f, a2 = 0.f, a3 = 0.f;
        float a4 = 0.f, a5 = 0.f, a6 = 0.f, a7 = 0.f;
        int deg = 1;
        if (node < N_NODES) {
            const int lo = rowoff[node];
            const int hi = rowoff[node + 1];
            deg = max(hi - lo, 1);
            if (BF) {
                int k = lo + g;
                for (; k + 4 < hi; k += 8) {  // 2 independent row loads in flight
                    int s0 = csr[k], s1 = csr[k + 4];
                    uint4 v = *reinterpret_cast<const uint4*>(hb + (size_t)s0 * DIM + c * 8);
                    uint4 w = *reinterpret_cast<const uint4*>(hb + (size_t)s1 * DIM + c * 8);
                    a0 += __uint_as_float(v.x << 16) + __uint_as_float(w.x << 16);
                    a1 += __uint_as_float(v.x & 0xffff0000u) + __uint_as_float(w.x & 0xffff0000u);
                    a2 += __uint_as_float(v.y << 16) + __uint_as_float(w.y << 16);
                    a3 += __uint_as_float(v.y & 0xffff0000u) + __uint_as_float(w.y & 0xffff0000u);
                    a4 += __uint_as_float(v.z << 16) + __uint_as_float(w.z << 16);
                    a5 += __uint_as_float(v.z & 0xffff0000u) + __uint_as_float(w.z & 0xffff0000u);
                    a6 += __uint_as_float(v.w << 16) + __uint_as_float(w.w << 16);
                    a7 += __uint_as_float(v.w & 0xffff0000u) + __uint_as_float(w.w & 0xffff0000u);
                }
                if (k < hi) {
                    uint4 v = *reinterpret_cast<const uint4*>(hb + (size_t)csr[k] * DIM + c * 8);
                    a0 += __uint_as_float(v.x << 16);
                    a1 += __uint_as_float(v.x & 0xffff0000u);
                    a2 += __uint_as_float(v.y << 16);
                    a3 += __uint_as_float(v.y & 0xffff0000u);
                    a4 += __uint_as_float(v.z << 16);
                    a5 += __uint_as_float(v.z & 0xffff0000u);
                    a6 += __uint_as_float(v.w << 16);
                    a7 += __uint_as_float(v.w & 0xffff0000u);
                }
            } else {
                for (int k = lo + g; k < hi; k += 4) {
                    int s = csr[k];
                    const float4* p = reinterpret_cast<const float4*>(h + (size_t)s * DIM + c * 8);
                    float4 x = p[0], y = p[1];
                    a0 += x.x; a1 += x.y; a2 += x.z; a3 += x.w;
                    a4 += y.x; a5 += y.y; a6 += y.z; a7 += y.w;
                }
            }
        }
        // sum the 4 edge-slot groups (lanes l, l^16, l^32, l^48)
        a0 += __shfl_xor(a0, 16, 64); a0 += __shfl_xor(a0, 32, 64);
        a1 += __shfl_xor(a1, 16, 64); a1 += __shfl_xor(a1, 32, 64);
        a2 += __shfl_xor(a2, 16, 64); a2 += __shfl_xor(a2, 32, 64);
        a3 += __shfl_xor(a3, 16, 64); a3 += __shfl_xor(a3, 32, 64);
        a4 += __shfl_xor(a4, 16, 64); a4 += __shfl_xor(a4, 32, 64);
        a5 += __shfl_xor(a5, 16, 64); a5 += __shfl_xor(a5, 32, 64);
        a6 += __shfl_xor(a6, 16, 64); a6 += __shfl_xor(a6, 32, 64);
        a7 += __shfl_xor(a7, 16, 64); a7 += __shfl_xor(a7, 32, 64);
        if (g == 0) {
            float inv = 1.0f / (float)deg;
            u16x8 rr;
            rr[0] = f2bf(a0 * inv); rr[1] = f2bf(a1 * inv);
            rr[2] = f2bf(a2 * inv); rr[3] = f2bf(a3 * inv);
            rr[4] = f2bf(a4 * inv); rr[5] = f2bf(a5 * inv);
            rr[6] = f2bf(a6 * inv); rr[7] = f2bf(a7 * inv);
            *reinterpret_cast<u16x8*>(&hnl[wid * 16 + r][c * 8]) = rr;
        }
    }
    // wave-private LDS rows: writes and reads by the same wave; the compiler's
    // lgkmcnt ordering covers the dependency — no __syncthreads needed.

    // ---- Phase 2: MFMA GEMM ----
    const int row = node_base + (lane & 15);
    const int rowc = min(row, N_NODES - 1);
    const int khi = lane >> 4;

    f32x4 acc[8] = {};
    const unsigned short* wn_p = wpack + 16384;

#pragma unroll
    for (int ks = 0; ks < 4; ++ks) {
        const int k0 = ks * 32 + khi * 8;
        bf16x8 ha;
        if (BF) {
            ha = *reinterpret_cast<const bf16x8*>(hb + (size_t)rowc * DIM + k0);
        } else {
            const float4* hp = reinterpret_cast<const float4*>(h + (size_t)rowc * DIM + k0);
            float4 x = hp[0], y = hp[1];
            ha[0] = (short)f2bf(x.x); ha[1] = (short)f2bf(x.y);
            ha[2] = (short)f2bf(x.z); ha[3] = (short)f2bf(x.w);
            ha[4] = (short)f2bf(y.x); ha[5] = (short)f2bf(y.y);
            ha[6] = (short)f2bf(y.z); ha[7] = (short)f2bf(y.w);
        }
        bf16x8 na = *reinterpret_cast<const bf16x8*>(&hnl[wid * 16 + (lane & 15)][k0]);

#pragma unroll
        for (int nt = 0; nt < 8; ++nt) {
            bf16x8 bs = *reinterpret_cast<const bf16x8*>(wpack + (size_t)(((nt * 4 + ks) * 64 + lane) * 8));
            acc[nt] = __builtin_amdgcn_mfma_f32_16x16x32_bf16(ha, bs, acc[nt], 0, 0, 0);
            bf16x8 bn = *reinterpret_cast<const bf16x8*>(wn_p + (size_t)(((nt * 4 + ks) * 64 + lane) * 8));
            acc[nt] = __builtin_amdgcn_mfma_f32_16x16x32_bf16(na, bn, acc[nt], 0, 0, 0);
        }
    }

    // C/D layout (verified m89): col = lane&15, row = (lane>>4)*4 + reg
    const int r0 = node_base + khi * 4;
#pragma unroll
    for (int nt = 0; nt < 8; ++nt) {
        int o = nt * 16 + (lane & 15);
        float bb = bavg[o];
#pragma unroll
        for (int r = 0; r < 4; ++r) {
            int nr = r0 + r;
            if (nr < N_NODES) out[(size_t)nr * DIM + o] = acc[nt][r] + bb;
        }
    }
}

extern "C" void kernel_launch(void* const* d_in, const int* in_sizes, int n_in,
                              void* d_out, int out_size, void* d_ws, size_t ws_size,
                              hipStream_t stream) {
    const float* h  = (const float*)d_in[0];
    const int* src  = (const int*)d_in[1];
    const int* dst  = (const int*)d_in[2];
    const float* Ws = (const float*)d_in[3];
    const float* Wn = (const float*)d_in[4];
    const float* b  = (const float*)d_in[5];
    float* out = (float*)d_out;

    char* ws = (char*)d_ws;
    int* bcnt   = (int*)(ws + B_BCNT);
    int* bbase  = (int*)(ws + B_BBASE);
    int* bcur   = (int*)(ws + B_BCUR);
    int* rowoff = (int*)(ws + B_ROWOFF);
    int* csr    = (int*)(ws + B_CSR);
    unsigned short* wpack = (unsigned short*)(ws + B_WPACK);
    float* bavg = (float*)(ws + B_BAVG);
    unsigned short* hb = (unsigned short*)(ws + B_HB);
    int* ebuf   = (int*)(ws + B_EBUF);  // aliases hb head; dead before h2bf16

    const bool bf = (ws_size >= NEED_BF16);

    prep_weights_kernel<<<64, 256, 0, stream>>>(Ws, Wn, b, wpack, bavg, bcnt);
    bucket_hist_kernel<<<NBLK, 256, 0, stream>>>(dst, bcnt);
    bucket_scan_kernel<<<1, 256, 0, stream>>>(bcnt, bbase, bcur);
    bucket_scatter_kernel<<<NBLK, 256, 0, stream>>>(src, dst, bcur, ebuf);
    csr_build_kernel<<<NB, 256, 0, stream>>>(bcnt, bbase, ebuf, rowoff, csr);
    if (bf) h2bf16_kernel<<<(N_NODES * DIM / 8) / 256, 256, 0, stream>>>(h, hb);
    const int fused_blocks = (N_NODES + 63) / 64;
    if (bf)
        gather_gemm_kernel<true><<<fused_blocks, 256, 0, stream>>>(h, hb, rowoff, csr, out, wpack, bavg);
    else
        gather_gemm_kernel<false><<<fused_blocks, 256, 0, stream>>>(h, hb, rowoff, csr, out, wpack, bavg);
}

// Round 9
// 151.826 us; speedup vs baseline: 1.2790x; 1.2790x over previous
//
#include <hip/hip_runtime.h>

#define N_NODES 100000
#define N_EDGES 1600000
#define DIM 128
#define NH 4

#define NPB 512                                   // nodes per coarse bucket
#define NB 196                                    // ceil(N_NODES / NPB)
#define CAP 12288                                 // padded bucket capacity (mean 8192, +45 sigma)
#define BCHUNK 8192                               // edges per scatter block
#define BEPT 32                                   // BCHUNK / 256
#define NBLK ((N_EDGES + BCHUNK - 1) / BCHUNK)    // 196

typedef __attribute__((ext_vector_type(8))) short bf16x8;
typedef __attribute__((ext_vector_type(4))) float f32x4;
typedef __attribute__((ext_vector_type(8))) unsigned short u16x8;

// ws layout, BYTE offsets:
//   bcur   : [0, 1024)           int[256] absolute bucket cursors (init t*CAP)
//   rowoff : [4096, 404096)      int[100000] packed (csr_lo<<9)|deg
//   bbase  : [404096, 405120)    int[256] dense csr bucket bases
//   csr    : [405504, 6805504)   int[1.6M] src ids, dense, bucketed+sorted by dst
//   wpack  : [6805504, 6871040)  bf16 MFMA-packed Ws|Wn
//   bavg   : [6871040, 6871552)  f32[128]
//   hb     : [6871552, 32471552) bf16 copy of h (25.6MB)
// ebuf (padded buckets, 256*CAP ints = 12.6MB) lives in d_out: dead before the
// gather overwrites out.
#define B_BCUR   0u
#define B_ROWOFF 4096u
#define B_BBASE  404096u
#define B_CSR    405504u
#define B_WPACK  6805504u
#define B_BAVG   6871040u
#define B_HB     6871552u
#define NEED_BF16 32869376ull

// branchless RTNE f32->bf16 (finite inputs; no NaN path)
__device__ inline unsigned short f2bf(float x) {
    union { float f; unsigned u; } v; v.f = x;
    unsigned r = v.u + 0x7fffu + ((v.u >> 16) & 1u);
    return (unsigned short)(r >> 16);
}

// ---------------------------------------------------------------------------
// prep: (all blocks, BF only) h -> bf16 copy; (blocks<64) head-averaged,
// MFMA-B-frag-packed weights; (block 0) bavg + absolute bucket cursors.
// ---------------------------------------------------------------------------
template <bool BF>
__global__ __launch_bounds__(256) void prep_kernel(
    const float* __restrict__ h, unsigned short* __restrict__ hb,
    const float* __restrict__ Ws, const float* __restrict__ Wn,
    const float* __restrict__ b, unsigned short* __restrict__ wpack,
    float* __restrict__ bavg, int* __restrict__ bcur) {
    const int t = threadIdx.x;
    if (blockIdx.x == 0) bcur[t] = t * CAP;
    int i = blockIdx.x * 256 + t;
    if (i < DIM * DIM) {
        float s = 0.f, n = 0.f;
#pragma unroll
        for (int hh = 0; hh < NH; ++hh) {
            s += Ws[hh * DIM * DIM + i];
            n += Wn[hh * DIM * DIM + i];
        }
        s *= 0.25f; n *= 0.25f;
        int k = i >> 7, o = i & 127;
        int nt = o >> 4, lanelo = o & 15;
        int ks = k >> 5, lanehi = (k & 31) >> 3, e = k & 7;
        int pos = (((nt * 4 + ks) * 64) + lanehi * 16 + lanelo) * 8 + e;
        wpack[pos] = f2bf(s);
        wpack[16384 + pos] = f2bf(n);
    }
    if (i < DIM) {
        float bb = 0.f;
#pragma unroll
        for (int hh = 0; hh < NH; ++hh) bb += b[hh * DIM + i];
        bavg[i] = 0.25f * bb;
    }
    if (BF) {  // 8 elems/thread bf16 conversion
        const float4* p = reinterpret_cast<const float4*>(h) + (size_t)i * 2;
        float4 a = p[0], c = p[1];
        u16x8 r;
        r[0] = f2bf(a.x); r[1] = f2bf(a.y); r[2] = f2bf(a.z); r[3] = f2bf(a.w);
        r[4] = f2bf(c.x); r[5] = f2bf(c.y); r[6] = f2bf(c.z); r[7] = f2bf(c.w);
        reinterpret_cast<u16x8*>(hb)[i] = r;
    }
}

// ---------------------------------------------------------------------------
// single-pass bucket scatter: block stages 8192 packed edges + bucket bytes in
// LDS, reserves per-bucket chunks from absolute cursors (1 global atomic per
// bucket per block), appends ~32-edge (128B) runs into the padded ebuf.
// Packed word: (src<<9) | (dst & 511).
// ---------------------------------------------------------------------------
__global__ __launch_bounds__(256) void bucket_scatter_kernel(const int* __restrict__ src,
                                                             const int* __restrict__ dst,
                                                             int* __restrict__ bcur,
                                                             int* __restrict__ ebuf) {
    __shared__ int stage[BCHUNK];
    __shared__ unsigned char bkt[BCHUNK];
    __shared__ int lc[256], lbase[256], lpos[256];
    int t = threadIdx.x;
    lc[t] = 0;
    lpos[t] = 0;
    __syncthreads();
    int e0 = blockIdx.x * BCHUNK;
#pragma unroll 4
    for (int j = 0; j < BEPT; ++j) {
        int e = e0 + j * 256 + t;
        if (e < N_EDGES) {
            int d = dst[e];
            stage[j * 256 + t] = (src[e] << 9) | (d & (NPB - 1));
            bkt[j * 256 + t] = (unsigned char)(d >> 9);
            atomicAdd(&lc[d >> 9], 1);
        }
    }
    __syncthreads();
    if (lc[t]) lbase[t] = atomicAdd(&bcur[t], lc[t]);
    __syncthreads();
#pragma unroll 4
    for (int j = 0; j < BEPT; ++j) {
        int e = e0 + j * 256 + t;
        if (e < N_EDGES) {
            int bb = bkt[j * 256 + t];
            int o = atomicAdd(&lpos[bb], 1);
            ebuf[lbase[bb] + o] = stage[j * 256 + t];
        }
    }
}

// ---------------------------------------------------------------------------
// scan the 256 final cursors -> dense csr bucket bases
// ---------------------------------------------------------------------------
__global__ __launch_bounds__(256) void bucket_scan_kernel(const int* __restrict__ bcur,
                                                          int* __restrict__ bbase) {
    __shared__ int s[256];
    int t = threadIdx.x;
    int v = bcur[t] - t * CAP;  // bucket count
    s[t] = v;
    __syncthreads();
    for (int off = 1; off < 256; off <<= 1) {
        int add = (t >= off) ? s[t - off] : 0;
        __syncthreads();
        s[t] += add;
        __syncthreads();
    }
    bbase[t] = s[t] - v;  // exclusive
}

// ---------------------------------------------------------------------------
// one block per bucket: local 512-slot hist + scan -> packed rowoff
// ((lo<<9)|deg), then scatter src into the dense csr window (L2-resident).
// ---------------------------------------------------------------------------
__global__ __launch_bounds__(256) void csr_build_kernel(const int* __restrict__ bcur,
                                                        const int* __restrict__ bbase,
                                                        const int* __restrict__ ebuf,
                                                        int* __restrict__ rowoff,
                                                        int* __restrict__ csr) {
    __shared__ int h[NPB], off[NPB], cur[NPB], ss[256];
    int b = blockIdx.x, t = threadIdx.x;
    int cnt = bcur[b] - b * CAP;
    int ibase = b * CAP;       // ebuf (padded) base
    int obase = bbase[b];      // csr (dense) base
    h[t] = 0; h[t + 256] = 0;
    cur[t] = 0; cur[t + 256] = 0;
    __syncthreads();
    for (int i = t; i < cnt; i += 256) atomicAdd(&h[ebuf[ibase + i] & (NPB - 1)], 1);
    __syncthreads();
    int e0 = h[2 * t], e1 = h[2 * t + 1];
    ss[t] = e0 + e1;
    __syncthreads();
    for (int o = 1; o < 256; o <<= 1) {
        int add = (t >= o) ? ss[t - o] : 0;
        __syncthreads();
        ss[t] += add;
        __syncthreads();
    }
    int ex = ss[t] - (e0 + e1);
    off[2 * t] = ex;
    off[2 * t + 1] = ex + e0;
    __syncthreads();
    int n0 = b * NPB;
#pragma unroll
    for (int k = 0; k < 2; ++k) {
        int s2 = 2 * t + k;
        int n = n0 + s2;
        int dg = (k == 0) ? e0 : e1;
        if (n < N_NODES) rowoff[n] = ((obase + off[s2]) << 9) | min(dg, 511);
    }
    for (int i = t; i < cnt; i += 256) {
        int p = ebuf[ibase + i];
        int nl = p & (NPB - 1);
        int o = atomicAdd(&cur[nl], 1);
        csr[obase + off[nl] + o] = p >> 9;
    }
}

// ---------------------------------------------------------------------------
// gather-mean: one wave per node; 4 edge-slots x 16 lanes, 16B per lane,
// 2 independent row loads in flight per slot. BF path stores the mean row as
// packed bf16 in the FIRST HALF of the node's out row (same rounding point as
// the GEMM's f2bf -> bitwise-identical final output).
// ---------------------------------------------------------------------------
template <bool BF>
__global__ __launch_bounds__(256) void gather_mean_kernel(
    const float* __restrict__ h, const unsigned short* __restrict__ hb,
    const int* __restrict__ rowoff, const int* __restrict__ csr,
    float* __restrict__ out) {
    int node = blockIdx.x * 4 + (threadIdx.x >> 6);
    int lane = threadIdx.x & 63;
    int g = lane >> 4;   // edge slot
    int c = lane & 15;   // 16B chunk within row (8 elems)
    int w = rowoff[node];
    int lo = w >> 9;
    int dg = w & 511;
    int hi = lo + dg;
    float a0 = 0.f, a1 = 0.f, a2 = 0.f, a3 = 0.f;
    float a4 = 0.f, a5 = 0.f, a6 = 0.f, a7 = 0.f;
    if (BF) {
        int k = lo + g;
        for (; k + 4 < hi; k += 8) {  // 2 independent row loads in flight
            int s0 = csr[k], s1 = csr[k + 4];
            uint4 v = *reinterpret_cast<const uint4*>(hb + (size_t)s0 * DIM + c * 8);
            uint4 ww = *reinterpret_cast<const uint4*>(hb + (size_t)s1 * DIM + c * 8);
            a0 += __uint_as_float(v.x << 16) + __uint_as_float(ww.x << 16);
            a1 += __uint_as_float(v.x & 0xffff0000u) + __uint_as_float(ww.x & 0xffff0000u);
            a2 += __uint_as_float(v.y << 16) + __uint_as_float(ww.y << 16);
            a3 += __uint_as_float(v.y & 0xffff0000u) + __uint_as_float(ww.y & 0xffff0000u);
            a4 += __uint_as_float(v.z << 16) + __uint_as_float(ww.z << 16);
            a5 += __uint_as_float(v.z & 0xffff0000u) + __uint_as_float(ww.z & 0xffff0000u);
            a6 += __uint_as_float(v.w << 16) + __uint_as_float(ww.w << 16);
            a7 += __uint_as_float(v.w & 0xffff0000u) + __uint_as_float(ww.w & 0xffff0000u);
        }
        if (k < hi) {
            uint4 v = *reinterpret_cast<const uint4*>(hb + (size_t)csr[k] * DIM + c * 8);
            a0 += __uint_as_float(v.x << 16);
            a1 += __uint_as_float(v.x & 0xffff0000u);
            a2 += __uint_as_float(v.y << 16);
            a3 += __uint_as_float(v.y & 0xffff0000u);
            a4 += __uint_as_float(v.z << 16);
            a5 += __uint_as_float(v.z & 0xffff0000u);
            a6 += __uint_as_float(v.w << 16);
            a7 += __uint_as_float(v.w & 0xffff0000u);
        }
    } else {
        for (int k = lo + g; k < hi; k += 4) {
            int s = csr[k];
            const float4* p = reinterpret_cast<const float4*>(h + (size_t)s * DIM + c * 8);
            float4 x = p[0], y = p[1];
            a0 += x.x; a1 += x.y; a2 += x.z; a3 += x.w;
            a4 += y.x; a5 += y.y; a6 += y.z; a7 += y.w;
        }
    }
    // sum the 4 edge-slot groups (lanes l, l^16, l^32, l^48)
    a0 += __shfl_xor(a0, 16, 64); a0 += __shfl_xor(a0, 32, 64);
    a1 += __shfl_xor(a1, 16, 64); a1 += __shfl_xor(a1, 32, 64);
    a2 += __shfl_xor(a2, 16, 64); a2 += __shfl_xor(a2, 32, 64);
    a3 += __shfl_xor(a3, 16, 64); a3 += __shfl_xor(a3, 32, 64);
    a4 += __shfl_xor(a4, 16, 64); a4 += __shfl_xor(a4, 32, 64);
    a5 += __shfl_xor(a5, 16, 64); a5 += __shfl_xor(a5, 32, 64);
    a6 += __shfl_xor(a6, 16, 64); a6 += __shfl_xor(a6, 32, 64);
    a7 += __shfl_xor(a7, 16, 64); a7 += __shfl_xor(a7, 32, 64);
    float inv = 1.0f / (float)max(dg, 1);
    if (g == 0) {
        if (BF) {
            u16x8 r;
            r[0] = f2bf(a0 * inv); r[1] = f2bf(a1 * inv);
            r[2] = f2bf(a2 * inv); r[3] = f2bf(a3 * inv);
            r[4] = f2bf(a4 * inv); r[5] = f2bf(a5 * inv);
            r[6] = f2bf(a6 * inv); r[7] = f2bf(a7 * inv);
            *reinterpret_cast<u16x8*>(reinterpret_cast<unsigned short*>(out) +
                                      (size_t)node * 256 + c * 8) = r;
        } else {
            float4 r0, r1;
            r0.x = a0 * inv; r0.y = a1 * inv; r0.z = a2 * inv; r0.w = a3 * inv;
            r1.x = a4 * inv; r1.y = a5 * inv; r1.z = a6 * inv; r1.w = a7 * inv;
            float4* q = reinterpret_cast<float4*>(out + (size_t)node * DIM + c * 8);
            q[0] = r0;
            q[1] = r1;
        }
    }
}

// ---------------------------------------------------------------------------
// MFMA GEMM: out[n] = h[n]@Ws + hn[n]@Wn + bavg. BF path: hn is packed bf16 in
// the first half of each out row (wave-local in-place overwrite). Wave = 16
// nodes x 128 outs, 4 k-steps x 16 MFMA.
// ---------------------------------------------------------------------------
template <bool BF>
__global__ __launch_bounds__(256) void mfma_gemm_kernel(
    const float* __restrict__ h, const unsigned short* __restrict__ hb,
    float* __restrict__ out, const unsigned short* __restrict__ wpack,
    const float* __restrict__ bavg) {
    const int lane = threadIdx.x & 63;
    const int wid = threadIdx.x >> 6;
    const int node_base = blockIdx.x * 64 + wid * 16;
    const int row = node_base + (lane & 15);
    const int rowc = min(row, N_NODES - 1);
    const int khi = lane >> 4;

    f32x4 acc[8] = {};
    const unsigned short* wn_p = wpack + 16384;

#pragma unroll
    for (int ks = 0; ks < 4; ++ks) {
        const int k0 = ks * 32 + khi * 8;
        bf16x8 ha, na;
        if (BF) {
            ha = *reinterpret_cast<const bf16x8*>(hb + (size_t)rowc * DIM + k0);
            na = *reinterpret_cast<const bf16x8*>(
                reinterpret_cast<const unsigned short*>(out) + (size_t)rowc * 256 + k0);
        } else {
            const float4* hp = reinterpret_cast<const float4*>(h + (size_t)rowc * DIM + k0);
            float4 x = hp[0], y = hp[1];
            ha[0] = (short)f2bf(x.x); ha[1] = (short)f2bf(x.y);
            ha[2] = (short)f2bf(x.z); ha[3] = (short)f2bf(x.w);
            ha[4] = (short)f2bf(y.x); ha[5] = (short)f2bf(y.y);
            ha[6] = (short)f2bf(y.z); ha[7] = (short)f2bf(y.w);
            const float4* np0 = reinterpret_cast<const float4*>(out + (size_t)rowc * DIM + k0);
            float4 u = np0[0], v = np0[1];
            na[0] = (short)f2bf(u.x); na[1] = (short)f2bf(u.y);
            na[2] = (short)f2bf(u.z); na[3] = (short)f2bf(u.w);
            na[4] = (short)f2bf(v.x); na[5] = (short)f2bf(v.y);
            na[6] = (short)f2bf(v.z); na[7] = (short)f2bf(v.w);
        }

#pragma unroll
        for (int nt = 0; nt < 8; ++nt) {
            bf16x8 bs = *reinterpret_cast<const bf16x8*>(wpack + (size_t)(((nt * 4 + ks) * 64 + lane) * 8));
            acc[nt] = __builtin_amdgcn_mfma_f32_16x16x32_bf16(ha, bs, acc[nt], 0, 0, 0);
            bf16x8 bn = *reinterpret_cast<const bf16x8*>(wn_p + (size_t)(((nt * 4 + ks) * 64 + lane) * 8));
            acc[nt] = __builtin_amdgcn_mfma_f32_16x16x32_bf16(na, bn, acc[nt], 0, 0, 0);
        }
    }

    // C/D layout (verified m89): col = lane&15, row = (lane>>4)*4 + reg
    const int r0 = node_base + khi * 4;
#pragma unroll
    for (int nt = 0; nt < 8; ++nt) {
        int o = nt * 16 + (lane & 15);
        float bb = bavg[o];
#pragma unroll
        for (int r = 0; r < 4; ++r) {
            int nr = r0 + r;
            if (nr < N_NODES) out[(size_t)nr * DIM + o] = acc[nt][r] + bb;
        }
    }
}

extern "C" void kernel_launch(void* const* d_in, const int* in_sizes, int n_in,
                              void* d_out, int out_size, void* d_ws, size_t ws_size,
                              hipStream_t stream) {
    const float* h  = (const float*)d_in[0];
    const int* src  = (const int*)d_in[1];
    const int* dst  = (const int*)d_in[2];
    const float* Ws = (const float*)d_in[3];
    const float* Wn = (const float*)d_in[4];
    const float* b  = (const float*)d_in[5];
    float* out = (float*)d_out;

    char* ws = (char*)d_ws;
    int* bcur   = (int*)(ws + B_BCUR);
    int* rowoff = (int*)(ws + B_ROWOFF);
    int* bbase  = (int*)(ws + B_BBASE);
    int* csr    = (int*)(ws + B_CSR);
    unsigned short* wpack = (unsigned short*)(ws + B_WPACK);
    float* bavg = (float*)(ws + B_BAVG);
    unsigned short* hb = (unsigned short*)(ws + B_HB);
    int* ebuf   = (int*)d_out;  // padded buckets (12.6MB); dead before gather

    const bool bf = (ws_size >= NEED_BF16);

    if (bf)
        prep_kernel<true><<<(N_NODES * DIM / 8) / 256, 256, 0, stream>>>(h, hb, Ws, Wn, b, wpack, bavg, bcur);
    else
        prep_kernel<false><<<64, 256, 0, stream>>>(h, hb, Ws, Wn, b, wpack, bavg, bcur);
    bucket_scatter_kernel<<<NBLK, 256, 0, stream>>>(src, dst, bcur, ebuf);
    bucket_scan_kernel<<<1, 256, 0, stream>>>(bcur, bbase);
    csr_build_kernel<<<NB, 256, 0, stream>>>(bcur, bbase, ebuf, rowoff, csr);
    if (bf)
        gather_mean_kernel<true><<<N_NODES / 4, 256, 0, stream>>>(h, hb, rowoff, csr, out);
    else
        gather_mean_kernel<false><<<N_NODES / 4, 256, 0, stream>>>(h, hb, rowoff, csr, out);
    const int gemm_blocks = (N_NODES + 63) / 64;
    if (bf)
        mfma_gemm_kernel<true><<<gemm_blocks, 256, 0, stream>>>(h, hb, out, wpack, bavg);
    else
        mfma_gemm_kernel<false><<<gemm_blocks, 256, 0, stream>>>(h, hb, out, wpack, bavg);
}

// Round 10
// 146.829 us; speedup vs baseline: 1.3226x; 1.0340x over previous
//
#include <hip/hip_runtime.h>

#define N_NODES 100000
#define N_EDGES 1600000
#define DIM 128
#define NH 4

#define NPB 512                                   // nodes per coarse bucket
#define NB 196                                    // ceil(N_NODES / NPB)
#define CAP 12288                                 // padded bucket capacity (mean 8192)
#define BCHUNK 8192                               // edges per scatter block
#define BEPT 32                                   // BCHUNK / 256
#define NBLK ((N_EDGES + BCHUNK - 1) / BCHUNK)    // 196

typedef __attribute__((ext_vector_type(8))) short bf16x8;
typedef __attribute__((ext_vector_type(4))) float f32x4;
typedef __attribute__((ext_vector_type(2))) float f32x2;
typedef __attribute__((ext_vector_type(8))) unsigned short u16x8;

// ws layout, BYTE offsets:
//   bcur   : [0, 1024)           int[256] absolute bucket cursors (init t*CAP)
//   rowoff : [4096, 404096)      int[100000] packed (csr_lo<<9)|deg
//   csr    : [405504, 6805504)   int[1.6M] src ids, dense, bucketed+sorted by dst
//   wpack  : [6805504, 6871040)  bf16 MFMA-packed Ws|Wn
//   bavg   : [6871040, 6871552)  f32[128]
//   h8     : [6871552, 19671552) fp8 e4m3 copy of h (12.8MB), neighbor path only
// ebuf (padded buckets, 256*CAP ints = 12.6MB) lives in d_out: dead before gather.
#define B_BCUR   0u
#define B_ROWOFF 4096u
#define B_CSR    405504u
#define B_WPACK  6805504u
#define B_BAVG   6871040u
#define B_H8     6871552u
#define NEED_BF16 32869376ull

// branchless RTNE f32->bf16 (finite inputs; no NaN path)
__device__ inline unsigned short f2bf(float x) {
    union { float f; unsigned u; } v; v.f = x;
    unsigned r = v.u + 0x7fffu + ((v.u >> 16) & 1u);
    return (unsigned short)(r >> 16);
}

// decode 16 fp8 e4m3 (uint4) -> accumulate into 16 f32 (HW cvt, 8 instrs)
__device__ inline void acc_fp8(float (&a)[16], uint4 v) {
    f32x2 r;
    r = __builtin_amdgcn_cvt_pk_f32_fp8((int)v.x, false); a[0] += r[0]; a[1] += r[1];
    r = __builtin_amdgcn_cvt_pk_f32_fp8((int)v.x, true);  a[2] += r[0]; a[3] += r[1];
    r = __builtin_amdgcn_cvt_pk_f32_fp8((int)v.y, false); a[4] += r[0]; a[5] += r[1];
    r = __builtin_amdgcn_cvt_pk_f32_fp8((int)v.y, true);  a[6] += r[0]; a[7] += r[1];
    r = __builtin_amdgcn_cvt_pk_f32_fp8((int)v.z, false); a[8] += r[0]; a[9] += r[1];
    r = __builtin_amdgcn_cvt_pk_f32_fp8((int)v.z, true);  a[10] += r[0]; a[11] += r[1];
    r = __builtin_amdgcn_cvt_pk_f32_fp8((int)v.w, false); a[12] += r[0]; a[13] += r[1];
    r = __builtin_amdgcn_cvt_pk_f32_fp8((int)v.w, true);  a[14] += r[0]; a[15] += r[1];
}

__device__ inline void acc_f32(float (&a)[16], const float4* p) {
    float4 x0 = p[0], x1 = p[1], x2 = p[2], x3 = p[3];
    a[0] += x0.x; a[1] += x0.y; a[2] += x0.z; a[3] += x0.w;
    a[4] += x1.x; a[5] += x1.y; a[6] += x1.z; a[7] += x1.w;
    a[8] += x2.x; a[9] += x2.y; a[10] += x2.z; a[11] += x2.w;
    a[12] += x3.x; a[13] += x3.y; a[14] += x3.z; a[15] += x3.w;
}

// ---------------------------------------------------------------------------
// prep: (F8, all blocks) h -> fp8 e4m3 copy; (blocks<64) head-averaged
// MFMA-B-frag-packed weights; (block 0) bavg + absolute bucket cursors.
// ---------------------------------------------------------------------------
template <bool F8>
__global__ __launch_bounds__(256) void prep_kernel(
    const float* __restrict__ h, unsigned char* __restrict__ h8,
    const float* __restrict__ Ws, const float* __restrict__ Wn,
    const float* __restrict__ b, unsigned short* __restrict__ wpack,
    float* __restrict__ bavg, int* __restrict__ bcur) {
    const int t = threadIdx.x;
    if (blockIdx.x == 0) bcur[t] = t * CAP;
    int i = blockIdx.x * 256 + t;
    if (i < DIM * DIM) {
        float s = 0.f, n = 0.f;
#pragma unroll
        for (int hh = 0; hh < NH; ++hh) {
            s += Ws[hh * DIM * DIM + i];
            n += Wn[hh * DIM * DIM + i];
        }
        s *= 0.25f; n *= 0.25f;
        int k = i >> 7, o = i & 127;
        int nt = o >> 4, lanelo = o & 15;
        int ks = k >> 5, lanehi = (k & 31) >> 3, e = k & 7;
        int pos = (((nt * 4 + ks) * 64) + lanehi * 16 + lanelo) * 8 + e;
        wpack[pos] = f2bf(s);
        wpack[16384 + pos] = f2bf(n);
    }
    if (i < DIM) {
        float bb = 0.f;
#pragma unroll
        for (int hh = 0; hh < NH; ++hh) bb += b[hh * DIM + i];
        bavg[i] = 0.25f * bb;
    }
    if (F8) {  // 8 elems/thread fp8 conversion (RTNE in HW)
        const float4* p = reinterpret_cast<const float4*>(h) + (size_t)i * 2;
        float4 a = p[0], c = p[1];
        int d0 = 0, d1 = 0;
        d0 = __builtin_amdgcn_cvt_pk_fp8_f32(a.x, a.y, d0, false);
        d0 = __builtin_amdgcn_cvt_pk_fp8_f32(a.z, a.w, d0, true);
        d1 = __builtin_amdgcn_cvt_pk_fp8_f32(c.x, c.y, d1, false);
        d1 = __builtin_amdgcn_cvt_pk_fp8_f32(c.z, c.w, d1, true);
        reinterpret_cast<uint2*>(h8)[i] = make_uint2((unsigned)d0, (unsigned)d1);
    }
}

// ---------------------------------------------------------------------------
// single-pass bucket scatter (absolute cursors; ~32-edge cacheline runs)
// ---------------------------------------------------------------------------
__global__ __launch_bounds__(256) void bucket_scatter_kernel(const int* __restrict__ src,
                                                             const int* __restrict__ dst,
                                                             int* __restrict__ bcur,
                                                             int* __restrict__ ebuf) {
    __shared__ int stage[BCHUNK];
    __shared__ unsigned char bkt[BCHUNK];
    __shared__ int lc[256], lbase[256], lpos[256];
    int t = threadIdx.x;
    lc[t] = 0;
    lpos[t] = 0;
    __syncthreads();
    int e0 = blockIdx.x * BCHUNK;
#pragma unroll 4
    for (int j = 0; j < BEPT; ++j) {
        int e = e0 + j * 256 + t;
        if (e < N_EDGES) {
            int d = dst[e];
            stage[j * 256 + t] = (src[e] << 9) | (d & (NPB - 1));
            bkt[j * 256 + t] = (unsigned char)(d >> 9);
            atomicAdd(&lc[d >> 9], 1);
        }
    }
    __syncthreads();
    if (lc[t]) lbase[t] = atomicAdd(&bcur[t], lc[t]);
    __syncthreads();
#pragma unroll 4
    for (int j = 0; j < BEPT; ++j) {
        int e = e0 + j * 256 + t;
        if (e < N_EDGES) {
            int bb = bkt[j * 256 + t];
            int o = atomicAdd(&lpos[bb], 1);
            ebuf[lbase[bb] + o] = stage[j * 256 + t];
        }
    }
}

// ---------------------------------------------------------------------------
// one block per bucket: internal 256-bucket scan (replaces bucket_scan
// dispatch), local 512-slot hist + scan -> packed rowoff ((lo<<9)|deg),
// then scatter src into the dense csr window (L2-resident).
// ---------------------------------------------------------------------------
__global__ __launch_bounds__(256) void csr_build_kernel(const int* __restrict__ bcur,
                                                        const int* __restrict__ ebuf,
                                                        int* __restrict__ rowoff,
                                                        int* __restrict__ csr) {
    __shared__ int hh[NPB], off[NPB], cur[NPB], ss[256];
    int b = blockIdx.x, t = threadIdx.x;
    int cnt = bcur[b] - b * CAP;
    int ibase = b * CAP;
    // internal exclusive scan of all 256 bucket counts -> obase
    ss[t] = bcur[t] - t * CAP;
    __syncthreads();
    for (int o = 1; o < 256; o <<= 1) {
        int add = (t >= o) ? ss[t - o] : 0;
        __syncthreads();
        ss[t] += add;
        __syncthreads();
    }
    int obase = ss[b] - cnt;
    hh[t] = 0; hh[t + 256] = 0;
    cur[t] = 0; cur[t + 256] = 0;
    __syncthreads();
    for (int i = t; i < cnt; i += 256) atomicAdd(&hh[ebuf[ibase + i] & (NPB - 1)], 1);
    __syncthreads();
    int e0 = hh[2 * t], e1 = hh[2 * t + 1];
    ss[t] = e0 + e1;
    __syncthreads();
    for (int o = 1; o < 256; o <<= 1) {
        int add = (t >= o) ? ss[t - o] : 0;
        __syncthreads();
        ss[t] += add;
        __syncthreads();
    }
    int ex = ss[t] - (e0 + e1);
    off[2 * t] = ex;
    off[2 * t + 1] = ex + e0;
    __syncthreads();
    int n0 = b * NPB;
#pragma unroll
    for (int k = 0; k < 2; ++k) {
        int s2 = 2 * t + k;
        int n = n0 + s2;
        int dgv = (k == 0) ? e0 : e1;
        if (n < N_NODES) rowoff[n] = ((obase + off[s2]) << 9) | min(dgv, 511);
    }
    for (int i = t; i < cnt; i += 256) {
        int p = ebuf[ibase + i];
        int nl = p & (NPB - 1);
        int o = atomicAdd(&cur[nl], 1);
        csr[obase + off[nl] + o] = p >> 9;
    }
}

// ---------------------------------------------------------------------------
// gather-mean: one wave per node; 8 edge-slots x 8 lanes x 16B, 2-deep ILP.
// F8 path reads fp8 rows (128B) via HW cvt; nodes with deg<8 take the fp32-row
// fallback (wave-uniform branch) to cap low-degree quantization variance.
// Mean row written as packed bf16 into the FIRST HALF of the node's out row.
// ---------------------------------------------------------------------------
template <bool F8>
__global__ __launch_bounds__(256) void gather_mean_kernel(
    const float* __restrict__ h, const unsigned char* __restrict__ h8,
    const int* __restrict__ rowoff, const int* __restrict__ csr,
    float* __restrict__ out) {
    const int node = blockIdx.x * 4 + (threadIdx.x >> 6);
    const int lane = threadIdx.x & 63;
    const int s = lane >> 3;   // edge slot 0..7
    const int c = lane & 7;    // 16-elem chunk 0..7
    const int w = rowoff[node];
    const int lo = w >> 9, dg = w & 511, hi = lo + dg;
    float a[16];
#pragma unroll
    for (int i = 0; i < 16; ++i) a[i] = 0.f;
    if (F8 && dg >= 8) {
        int k = lo + s;
        for (; k + 8 < hi; k += 16) {  // 2 independent row loads in flight
            int s0 = csr[k], s1 = csr[k + 8];
            uint4 v = *reinterpret_cast<const uint4*>(h8 + (size_t)s0 * DIM + c * 16);
            uint4 u = *reinterpret_cast<const uint4*>(h8 + (size_t)s1 * DIM + c * 16);
            acc_fp8(a, v);
            acc_fp8(a, u);
        }
        for (; k < hi; k += 8) {
            uint4 v = *reinterpret_cast<const uint4*>(h8 + (size_t)csr[k] * DIM + c * 16);
            acc_fp8(a, v);
        }
    } else {
        for (int k = lo + s; k < hi; k += 8)
            acc_f32(a, reinterpret_cast<const float4*>(h + (size_t)csr[k] * DIM + c * 16));
    }
    // reduce across the 8 slots (lane bits 3..5)
#pragma unroll
    for (int i = 0; i < 16; ++i) {
        a[i] += __shfl_xor(a[i], 8, 64);
        a[i] += __shfl_xor(a[i], 16, 64);
        a[i] += __shfl_xor(a[i], 32, 64);
    }
    float inv = 1.0f / (float)max(dg, 1);
    if (s == 0) {
        if (F8) {
            u16x8 r0, r1;
#pragma unroll
            for (int j = 0; j < 8; ++j) {
                r0[j] = f2bf(a[j] * inv);
                r1[j] = f2bf(a[8 + j] * inv);
            }
            unsigned short* base = reinterpret_cast<unsigned short*>(out) + (size_t)node * 256 + c * 16;
            *reinterpret_cast<u16x8*>(base) = r0;
            *reinterpret_cast<u16x8*>(base + 8) = r1;
        } else {
            float4* q = reinterpret_cast<float4*>(out + (size_t)node * DIM + c * 16);
            q[0] = make_float4(a[0] * inv, a[1] * inv, a[2] * inv, a[3] * inv);
            q[1] = make_float4(a[4] * inv, a[5] * inv, a[6] * inv, a[7] * inv);
            q[2] = make_float4(a[8] * inv, a[9] * inv, a[10] * inv, a[11] * inv);
            q[3] = make_float4(a[12] * inv, a[13] * inv, a[14] * inv, a[15] * inv);
        }
    }
}

// ---------------------------------------------------------------------------
// MFMA GEMM: out[n] = h[n]@Ws + hn[n]@Wn + bavg. Self path reads h fp32 +
// f2bf (bf16 quality); hn is packed bf16 in the first half of each out row
// (wave-local in-place overwrite). Wave = 16 nodes x 128 outs, 4 k-steps.
// ---------------------------------------------------------------------------
template <bool F8>
__global__ __launch_bounds__(256) void mfma_gemm_kernel(
    const float* __restrict__ h, float* __restrict__ out,
    const unsigned short* __restrict__ wpack, const float* __restrict__ bavg) {
    const int lane = threadIdx.x & 63;
    const int wid = threadIdx.x >> 6;
    const int node_base = blockIdx.x * 64 + wid * 16;
    const int row = node_base + (lane & 15);
    const int rowc = min(row, N_NODES - 1);
    const int khi = lane >> 4;

    f32x4 acc[8] = {};
    const unsigned short* wn_p = wpack + 16384;

#pragma unroll
    for (int ks = 0; ks < 4; ++ks) {
        const int k0 = ks * 32 + khi * 8;
        bf16x8 ha, na;
        const float4* hp = reinterpret_cast<const float4*>(h + (size_t)rowc * DIM + k0);
        float4 x = hp[0], y = hp[1];
        ha[0] = (short)f2bf(x.x); ha[1] = (short)f2bf(x.y);
        ha[2] = (short)f2bf(x.z); ha[3] = (short)f2bf(x.w);
        ha[4] = (short)f2bf(y.x); ha[5] = (short)f2bf(y.y);
        ha[6] = (short)f2bf(y.z); ha[7] = (short)f2bf(y.w);
        if (F8) {
            na = *reinterpret_cast<const bf16x8*>(
                reinterpret_cast<const unsigned short*>(out) + (size_t)rowc * 256 + k0);
        } else {
            const float4* np0 = reinterpret_cast<const float4*>(out + (size_t)rowc * DIM + k0);
            float4 u = np0[0], v = np0[1];
            na[0] = (short)f2bf(u.x); na[1] = (short)f2bf(u.y);
            na[2] = (short)f2bf(u.z); na[3] = (short)f2bf(u.w);
            na[4] = (short)f2bf(v.x); na[5] = (short)f2bf(v.y);
            na[6] = (short)f2bf(v.z); na[7] = (short)f2bf(v.w);
        }

#pragma unroll
        for (int nt = 0; nt < 8; ++nt) {
            bf16x8 bs = *reinterpret_cast<const bf16x8*>(wpack + (size_t)(((nt * 4 + ks) * 64 + lane) * 8));
            acc[nt] = __builtin_amdgcn_mfma_f32_16x16x32_bf16(ha, bs, acc[nt], 0, 0, 0);
            bf16x8 bn = *reinterpret_cast<const bf16x8*>(wn_p + (size_t)(((nt * 4 + ks) * 64 + lane) * 8));
            acc[nt] = __builtin_amdgcn_mfma_f32_16x16x32_bf16(na, bn, acc[nt], 0, 0, 0);
        }
    }

    // C/D layout (verified m89): col = lane&15, row = (lane>>4)*4 + reg
    const int r0 = node_base + khi * 4;
#pragma unroll
    for (int nt = 0; nt < 8; ++nt) {
        int o = nt * 16 + (lane & 15);
        float bb = bavg[o];
#pragma unroll
        for (int r = 0; r < 4; ++r) {
            int nr = r0 + r;
            if (nr < N_NODES) out[(size_t)nr * DIM + o] = acc[nt][r] + bb;
        }
    }
}

extern "C" void kernel_launch(void* const* d_in, const int* in_sizes, int n_in,
                              void* d_out, int out_size, void* d_ws, size_t ws_size,
                              hipStream_t stream) {
    const float* h  = (const float*)d_in[0];
    const int* src  = (const int*)d_in[1];
    const int* dst  = (const int*)d_in[2];
    const float* Ws = (const float*)d_in[3];
    const float* Wn = (const float*)d_in[4];
    const float* b  = (const float*)d_in[5];
    float* out = (float*)d_out;

    char* ws = (char*)d_ws;
    int* bcur   = (int*)(ws + B_BCUR);
    int* rowoff = (int*)(ws + B_ROWOFF);
    int* csr    = (int*)(ws + B_CSR);
    unsigned short* wpack = (unsigned short*)(ws + B_WPACK);
    float* bavg = (float*)(ws + B_BAVG);
    unsigned char* h8 = (unsigned char*)(ws + B_H8);
    int* ebuf   = (int*)d_out;  // padded buckets (12.6MB); dead before gather

    const bool f8 = (ws_size >= NEED_BF16);

    if (f8)
        prep_kernel<true><<<(N_NODES * DIM / 8) / 256, 256, 0, stream>>>(h, h8, Ws, Wn, b, wpack, bavg, bcur);
    else
        prep_kernel<false><<<64, 256, 0, stream>>>(h, h8, Ws, Wn, b, wpack, bavg, bcur);
    bucket_scatter_kernel<<<NBLK, 256, 0, stream>>>(src, dst, bcur, ebuf);
    csr_build_kernel<<<NB, 256, 0, stream>>>(bcur, ebuf, rowoff, csr);
    if (f8)
        gather_mean_kernel<true><<<N_NODES / 4, 256, 0, stream>>>(h, h8, rowoff, csr, out);
    else
        gather_mean_kernel<false><<<N_NODES / 4, 256, 0, stream>>>(h, h8, rowoff, csr, out);
    const int gemm_blocks = (N_NODES + 63) / 64;
    if (f8)
        mfma_gemm_kernel<true><<<gemm_blocks, 256, 0, stream>>>(h, out, wpack, bavg);
    else
        mfma_gemm_kernel<false><<<gemm_blocks, 256, 0, stream>>>(h, out, wpack, bavg);
}